// Round 11
// baseline (149.698 us; speedup 1.0000x reference)
//
#include <hip/hip_runtime.h>
#include <math.h>

#define S_LEN 1024
#define EPS 1e-6f

typedef __attribute__((ext_vector_type(8)))  short bf16x8;
typedef __attribute__((ext_vector_type(4)))  short bf16x4;
typedef __attribute__((ext_vector_type(16))) float float16v;

// Workspace layout (bytes):
//   kcnt2  : int  [32*64*32]      @ 0          (262144)  [bh][dim][seg]
//   qcnt2  : int  [32*64*32]      @ 262144     (262144)  [bh][dim][seg]
//   klist2 : ushort [2048*1024]   @ 524288     (4194304) [(bh,dim)][seg*32+pos]
//   qpair  : uint [2048*1024]     @ 4718592    (8388608) packed (w18|rank4|s10)
//   --- scatter extension (ws_size >= 64004096) ---
//   qflag  : uchar [32768]        @ 30416896   (32768)   1 = tie row (atomic path)
//   Obuf   : ushort [32768*8*64]  @ 30449664   (33554432) bf16 rank-slot rows
// R11 = R10 (one-shot parallel build staging, best 130.3us) + NSPLIT=2 query
// split (4096 blocks, R5's verified jlo/jhi windowed-gather pattern): now
// that the build is cheap (1 RT + 1 barrier), duplicating it per split costs
// ~1 L2-hit RT while halving each block's query chain and doubling queued
// blocks/CU (8 -> 16 vs the 5-resident LDS cap) -- reverses R6's unsplit,
// whose rationale (expensive build) R10 removed.

// lgkm-only barrier: __syncthreads() would force vmcnt(0), draining in-flight
// global stores/atomics + prefetch loads. Intra-block hazards here are
// LDS-only; global loads are register-consumed (compiler inserts counted
// vmcnt); stores/atomics are never read back in-kernel.
__device__ __forceinline__ void bar_lgkm() {
    asm volatile("s_waitcnt lgkmcnt(0)" ::: "memory");
    __builtin_amdgcn_s_barrier();
    __builtin_amdgcn_sched_barrier(0);
    asm volatile("" ::: "memory");
}

// VGPR anchor (rule #17): forces materialization at this program point
// (defeats load-sinking; R3 k_pre VGPR=20 showed loads sunk into loops).
#define PIN(x) asm volatile("" : "+v"(x))

__device__ __forceinline__ unsigned short f2bf(float f) {
    unsigned int u = __float_as_uint(f);
    unsigned int r = (u + 0x7fffu + ((u >> 16) & 1u)) >> 16;
    return (unsigned short)r;
}

__device__ __forceinline__ bf16x8 pack8(float4 a, float4 b) {
    bf16x8 r;
    r[0] = (short)f2bf(a.x); r[1] = (short)f2bf(a.y);
    r[2] = (short)f2bf(a.z); r[3] = (short)f2bf(a.w);
    r[4] = (short)f2bf(b.x); r[5] = (short)f2bf(b.y);
    r[6] = (short)f2bf(b.z); r[7] = (short)f2bf(b.w);
    return r;
}

// 1024 blocks = (bh, seg), 512 threads = 8 waves x 4 positions. (R10 verbatim)
__global__ __launch_bounds__(512) void k_pre(const float* __restrict__ keys,
                                             const float* __restrict__ queries,
                                             int* __restrict__ kcnt2,
                                             unsigned short* __restrict__ klist2,
                                             int* __restrict__ qcnt2,
                                             unsigned* __restrict__ qpair,
                                             unsigned char* __restrict__ qflag,
                                             float* __restrict__ out) {
    const int bh   = blockIdx.x >> 5;
    const int blk  = blockIdx.x & 31;          // segment id
    const int wv   = threadIdx.x >> 6;         // 0..7
    const int lane = threadIdx.x & 63;

    __shared__ int khist[64], qhist[64];
    __shared__ alignas(16) unsigned rq_s[8][4][64];   // 8 KB: per-wave row stage
    if (threadIdx.x < 64) { khist[threadIdx.x] = 0; qhist[threadIdx.x] = 0; }
    __syncthreads();

    const int s0 = blk * 32 + wv * 4;
    float kv[4], qv[4];
    #pragma unroll
    for (int i = 0; i < 4; ++i) {              // all loads issued up-front
        kv[i] = keys   [((size_t)bh * 1024 + s0 + i) * 64 + lane];
        qv[i] = queries[((size_t)bh * 1024 + s0 + i) * 64 + lane];
    }

    // zero d_out slice (independent store, issues inside the load shadow)
    {
        float4 zz = {0.f, 0.f, 0.f, 0.f};
        float4* po = (float4*)(out + (size_t)blockIdx.x * 2048);
        po[threadIdx.x] = zz;
    }

    // anchor: one vmcnt wait for all 8 loads; compute below is register/LDS
    #pragma unroll
    for (int i = 0; i < 4; ++i) { PIN(kv[i]); PIN(qv[i]); }

    // stage |q| bits to LDS (wave-private rows)
    unsigned ud[4];
    #pragma unroll
    for (int i = 0; i < 4; ++i) {
        ud[i] = __float_as_uint(qv[i]) & 0x7fffffffu;
        rq_s[wv][i][lane] = ud[i];
    }

    // ---- keys: 4 interleaved wave-argmaxes ----
    float bv[4]; int bi[4];
    #pragma unroll
    for (int i = 0; i < 4; ++i) { bv[i] = fabsf(kv[i]); bi[i] = lane; }
    #pragma unroll
    for (int off = 1; off < 64; off <<= 1) {
        #pragma unroll
        for (int i = 0; i < 4; ++i) {
            float ov = __shfl_xor(bv[i], off, 64);
            int   oi = __shfl_xor(bi[i], off, 64);
            if (ov > bv[i] || (ov == bv[i] && oi < bi[i])) { bv[i] = ov; bi[i] = oi; }
        }
    }
    #pragma unroll
    for (int i = 0; i < 4; ++i) {
        if (lane == 0) {
            int pos = atomicAdd(&khist[bi[i]], 1);
            klist2[((size_t)bh * 64 + bi[i]) * 1024 + blk * 32 + pos] =
                (unsigned short)(s0 + i);
        }
    }

    // ---- queries: rank via LDS uint4 broadcast (same-addr, conflict-free) ----
    int gt[4] = {0, 0, 0, 0};
    #pragma unroll
    for (int k4 = 0; k4 < 16; ++k4) {
        #pragma unroll
        for (int i = 0; i < 4; ++i) {
            const uint4 vv = *(const uint4*)&rq_s[wv][i][k4 * 4];
            gt[i] += (vv.x > ud[i]) ? 1 : 0;
            gt[i] += (vv.y > ud[i]) ? 1 : 0;
            gt[i] += (vv.z > ud[i]) ? 1 : 0;
            gt[i] += (vv.w > ud[i]) ? 1 : 0;
        }
    }
    int S[4];                                  // permutation check for ties
    #pragma unroll
    for (int i = 0; i < 4; ++i) S[i] = gt[i];
    #pragma unroll
    for (int off = 1; off < 64; off <<= 1) {
        #pragma unroll
        for (int i = 0; i < 4; ++i) S[i] += __shfl_xor(S[i], off, 64);
    }
    float e[4];
    #pragma unroll
    for (int i = 0; i < 4; ++i) e[i] = expf(__uint_as_float(ud[i]));
    int copies[4], contrib[4], rank[4];
    #pragma unroll
    for (int i = 0; i < 4; ++i) {
        if (S[i] == 2016) {                    // no ties (wave-uniform branch)
            contrib[i] = (gt[i] < 8);
            copies[i]  = contrib[i] ? 2 : 0;
            rank[i]    = gt[i];                // unique slot 0..7
        } else {                               // exact tie handling (rare)
            int eq = 0, eql = 0;
            #pragma unroll
            for (int k = 0; k < 64; ++k) {
                unsigned ui = (unsigned)__builtin_amdgcn_readlane((int)ud[i], k);
                eq  += (ui == ud[i]) ? 1 : 0;
                eql += (ui == ud[i] && k < lane) ? 1 : 0;
            }
            int pos_low  = 2 * gt[i] + eql;
            int pos_high = pos_low + eq;       // eq includes self
            copies[i]  = (pos_low < 16 ? 1 : 0) + (pos_high < 16 ? 1 : 0);
            contrib[i] = (pos_low < 16);
            rank[i]    = 15;                   // sentinel -> atomic path
        }
    }
    float ce[4];
    #pragma unroll
    for (int i = 0; i < 4; ++i) ce[i] = (float)copies[i] * e[i];
    #pragma unroll
    for (int off = 1; off < 64; off <<= 1) {
        #pragma unroll
        for (int i = 0; i < 4; ++i) ce[i] += __shfl_xor(ce[i], off, 64);
    }
    #pragma unroll
    for (int i = 0; i < 4; ++i) {
        if (contrib[i]) {
            int pos = atomicAdd(&qhist[lane], 1);
            unsigned wb = __float_as_uint(e[i] / ce[i]) & 0xFFFFC000u;  // 18-bit w
            qpair[((size_t)bh * 64 + lane) * 1024 + blk * 32 + pos] =
                wb | ((unsigned)rank[i] << 10) | (unsigned)(s0 + i);
        }
        if (qflag && lane == 0)
            qflag[bh * 1024 + s0 + i] = (S[i] == 2016) ? 0 : 1;
    }
    __syncthreads();
    if (threadIdx.x < 64) {                    // transposed [bh][dim][seg]
        kcnt2[(bh * 64 + threadIdx.x) * 32 + blk] = khist[threadIdx.x];
        qcnt2[(bh * 64 + threadIdx.x) * 32 + blk] = qhist[threadIdx.x];
    }
}

// 4096 blocks = (bh, bank, split). R11: each block builds M (cheap one-shot
// R10 staging) and handles HALF its bank's query list (R5's verified jlo/jhi
// windowed-gather pattern). SC: flush -> rank-addressed Obuf slots (plain
// stores); rank-15 ties -> atomics; k_reduce sums.
template <bool SC>
__global__ __launch_bounds__(256) void k_mainB(const float* __restrict__ keys,
                                               const float* __restrict__ values,
                                               const float* __restrict__ queries,
                                               const int* __restrict__ kcnt2,
                                               const unsigned short* __restrict__ klist2,
                                               const int* __restrict__ qcnt2,
                                               const unsigned* __restrict__ qpair,
                                               unsigned short* __restrict__ Obuf,
                                               float* __restrict__ out) {
    const int g     = blockIdx.x;      // 0..4095
    const int gb    = g >> 1;
    const int split = g & 1;
    const int bh    = gb >> 6;
    const int bank  = gb & 63;
    const int t     = threadIdx.x;
    const int lane  = t & 63;
    const int grp   = t >> 6;

    __shared__ alignas(16) unsigned short M_bf[64 * 64];   // 8 KB
    __shared__ alignas(16) unsigned short Q_bf[64 * 64];   // 8 KB (build: k-scratch f32)
    __shared__ alignas(16) unsigned short Ou_bf[64 * 68];  // 8.7 KB (build: v-scratch f32)
    __shared__ unsigned short s_match[256];
    __shared__ unsigned q_ent[256];
    __shared__ int    koffs_s[33], qoffs_s[33];
    __shared__ float  z_s[64];
    __shared__ double den_s[64];
    __shared__ float  w_s[2][64];
    __shared__ int    sq_s[2][64];

    // dual prefix scan: lanes 0-31 keys, 32-63 queries (contiguous counts)
    if (t < 64) {
        int i = t & 31;
        int c = (t < 32) ? kcnt2[(bh * 64 + bank) * 32 + i]
                         : qcnt2[(bh * 64 + bank) * 32 + i];
        #pragma unroll
        for (int off = 1; off < 32; off <<= 1) {
            int o = __shfl(c, t - off, 64);    // guarded by i >= off
            if (i >= off) c += o;
        }
        if (t < 32) { if (i == 0) koffs_s[0] = 0; koffs_s[i + 1] = c; }
        else        { if (i == 0) qoffs_s[0] = 0; qoffs_s[i + 1] = c; }
    }
    bar_lgkm();

    const int nq = qoffs_s[32];
    const int nm = koffs_s[32];
    const int half = (nq + 1) >> 1;
    const int jlo  = split * half;
    const int jhi  = min(nq, jlo + half);
    const int nqL  = jhi - jlo;
    if (nqL <= 0) return;
    const size_t listbase = (size_t)(bh * 64 + bank) * 1024;
    if (nm == 0) {
        // SC: empty bank still owns Obuf slots for its entries -> zero-fill
        if constexpr (SC) {
            for (int jg = jlo + t; jg < jhi; jg += 256) {
                int seg = 0;
                #pragma unroll
                for (int i = 1; i < 32; ++i) if (jg >= qoffs_s[i]) seg = i;
                unsigned e = qpair[listbase + seg * 32 + (jg - qoffs_s[seg])];
                int r = (e >> 10) & 15;
                if (r < 8) {
                    uint4 z4 = {0u, 0u, 0u, 0u};
                    uint4* dst = (uint4*)&Obuf[(((size_t)bh * 1024 +
                                 (e & 1023u)) * 8 + r) * 64];
                    #pragma unroll
                    for (int x = 0; x < 8; ++x) dst[x] = z4;
                }
            }
        }
        return;
    }

    // ---- phase 2: both chunk-0 gathers issued together (one bar) ----
    {
        if (t < min(256, nm)) {                // klist chunk 0
            int seg = 0;
            #pragma unroll
            for (int i = 1; i < 32; ++i) if (t >= koffs_s[i]) seg = i;
            s_match[t] = klist2[listbase + seg * 32 + (t - koffs_s[seg])];
        }
        if (t < 256 && t < nqL) {              // q_ent chunk 0 (hides under build)
            int jg = jlo + t;
            int seg = 0;
            #pragma unroll
            for (int i = 1; i < 32; ++i) if (jg >= qoffs_s[i]) seg = i;
            q_ent[t] = qpair[listbase + seg * 32 + (jg - qoffs_s[seg])];
        }
    }
    bar_lgkm();

    // ---- build M[dv][dk] = sum_s v[s][dv]*k[s][dk], z[dk] = sum_s k[s][dk]
    // R10: whole 32-key chunk staged at once -> 1 parallel RT + 1 barrier.
    {
        float* kstf = (float*)Q_bf;            // 32x64 f32 = 8 KB (Q_bf dead)
        float* vstf = (float*)Ou_bf;           // 32x64 f32 = 8 KB (Ou_bf dead)
        float acc[16];
        #pragma unroll
        for (int m = 0; m < 16; ++m) acc[m] = 0.f;
        float zacc = 0.f;
        const float* kb = keys   + (size_t)bh * S_LEN * 64;
        const float* vb = values + (size_t)bh * S_LEN * 64;
        int win = 0;                           // s_match window base
        for (int cb = 0; cb < nm; cb += 32) {
            const int cn = min(32, nm - cb);
            if ((cb & ~255) != win) {          // refill window (nm>256: ~never)
                bar_lgkm();
                win = cb & ~255;
                int wn = min(256, nm - win);
                if (t < wn) {
                    int idx = win + t, seg = 0;
                    #pragma unroll
                    for (int i = 1; i < 32; ++i) if (idx >= koffs_s[i]) seg = i;
                    s_match[t] = klist2[listbase + seg * 32 + (idx - koffs_s[seg])];
                }
                bar_lgkm();
            }
            if (cb > 0) bar_lgkm();            // prev chunk's scratch reads done
            {
                int r = t >> 3, c8 = t & 7;
                if (r < cn) {
                    int s = s_match[(cb - win) + r];
                    const float4* ks = (const float4*)(kb + (size_t)s * 64 + c8 * 8);
                    float4 k0 = ks[0], k1 = ks[1];
                    const float4* vs = (const float4*)(vb + (size_t)s * 64 + c8 * 8);
                    float4 w0 = vs[0], w1 = vs[1];
                    float4* kd = (float4*)&kstf[r * 64 + c8 * 8];
                    kd[0] = k0; kd[1] = k1;
                    float4* vd = (float4*)&vstf[r * 64 + c8 * 8];
                    vd[0] = w0; vd[1] = w1;
                }
            }
            bar_lgkm();                        // staging visible (1 barrier/chunk)
            for (int r = 0; r < cn; ++r) {
                float kv = kstf[r * 64 + lane];        // dk = lane (coalesced)
                #pragma unroll
                for (int m = 0; m < 16; ++m)           // dv = grp*16+m (broadcast)
                    acc[m] += vstf[r * 64 + grp * 16 + m] * kv;
            }
            if (t < 64)
                for (int r = 0; r < cn; ++r) zacc += kstf[r * 64 + t];
        }
        // write M as bf16, row-major [dv][dk], 16B-chunk XOR swizzle
        #pragma unroll
        for (int m = 0; m < 16; ++m) {
            int dv = grp * 16 + m;
            M_bf[dv * 64 + (((lane >> 3) ^ (dv & 7)) << 3) + (lane & 7)] = f2bf(acc[m]);
        }
        if (t < 64) z_s[t] = zacc;
    }
    bar_lgkm();                        // M_bf/z_s visible; scratch reads done

    // ---- query loop over [jlo, jhi): pipelined + prefetched (R5 pattern) ----
    const float* qb = queries + (size_t)bh * S_LEN * 64;
    float*       ob = out     + (size_t)bh * S_LEN * 64;
    unsigned short* obuf_b = SC ? Obuf + (size_t)bh * 1024 * 512 : nullptr;
    const int dvh = grp >> 1, jh = grp & 1;            // wave's 32x32 tile
    const int hi  = lane >> 5;
    const int jq  = t >> 2, cq = t & 3;                // stage mapping

    int prev_nb = 0;
    bool have_pf = false;                              // next-batch q row in regs
    float4 f0, f1, f2, f3;
    unsigned pe = 0;
    for (int qloc = 0, batch = 0; qloc < nqL; qloc += 64, ++batch) {
        const int nb  = min(64, nqL - qloc);
        const int cur = batch & 1;

        if (qloc != 0 && (qloc & 255) == 0) {  // refill q_ent past chunk 0
            if (qloc + t < nqL) {
                int jg = jlo + qloc + t;
                int seg = 0;
                #pragma unroll
                for (int i = 1; i < 32; ++i) if (jg >= qoffs_s[i]) seg = i;
                q_ent[t] = qpair[listbase + seg * 32 + (jg - qoffs_s[seg])];
            }
            bar_lgkm();
        }

        // A1: entry + cold q loads issued FIRST (don't queue behind stores)
        unsigned e = 0;
        const bool act = (jq < nb);
        if (act) {
            e = have_pf ? pe : q_ent[(qloc & 255) + jq];
            if (!have_pf) {
                const float4* src =
                    (const float4*)(qb + (size_t)(e & 1023u) * 64 + cq * 16);
                f0 = src[0]; f1 = src[1]; f2 = src[2]; f3 = src[3];
            }
        }

        // A2: flush previous batch (SC: plain bf16 stores to rank slots;
        // rank-15 tie entries keep atomic add; fire-and-forget either way)
        if (batch > 0) {
            #pragma unroll
            for (int jj = 0; jj < 16; ++jj) {
                int j = grp * 16 + jj;
                if (j < prev_nb) {
                    unsigned short vb16 = Ou_bf[j * 68 + lane];
                    int sr = sq_s[1 - cur][j];
                    int s  = sr & 1023;
                    if constexpr (SC) {
                        int r = (sr >> 10) & 15;
                        if (r < 8)
                            obuf_b[((size_t)s * 8 + r) * 64 + lane] = vb16;
                        else
                            unsafeAtomicAdd(&ob[(size_t)s * 64 + lane],
                                __uint_as_float((unsigned)vb16 << 16));
                    } else {
                        unsafeAtomicAdd(&ob[(size_t)s * 64 + lane],
                            __uint_as_float((unsigned)vb16 << 16));
                    }
                }
            }
        }

        // A3: pack + denominator + LDS stage
        {
            bf16x8 p0 = {}, p1 = {};
            double d = 0.0;
            if (act) {
                if ((t & 3) == 0) {
                    sq_s[cur][jq] = (int)(e & 0x3FFFu);        // s | rank<<10
                    w_s[cur][jq]  = __uint_as_float(e & 0xFFFFC000u);
                }
                p0 = pack8(f0, f1);
                p1 = pack8(f2, f3);
                const float4* zz4 = (const float4*)&z_s[cq * 16];
                float4 z0 = zz4[0], z1 = zz4[1], z2 = zz4[2], z3 = zz4[3];
                double da, db;
                da  = (double)z0.x * f0.x + (double)z0.y * f0.y + (double)z0.z * f0.z + (double)z0.w * f0.w;
                db  = (double)z1.x * f1.x + (double)z1.y * f1.y + (double)z1.z * f1.z + (double)z1.w * f1.w;
                da += (double)z2.x * f2.x + (double)z2.y * f2.y + (double)z2.z * f2.z + (double)z2.w * f2.w;
                db += (double)z3.x * f3.x + (double)z3.y * f3.y + (double)z3.z * f3.z + (double)z3.w * f3.w;
                d = da + db;
            }
            int c0 = cq * 2;
            *(bf16x8*)&Q_bf[jq * 64 + ((c0 ^ (jq & 7)) << 3)]       = p0;
            *(bf16x8*)&Q_bf[jq * 64 + (((c0 + 1) ^ (jq & 7)) << 3)] = p1;
            d += __shfl_xor(d, 1, 64);
            d += __shfl_xor(d, 2, 64);
            if ((t & 3) == 0) den_s[jq] = d;
        }

        // A4: prefetch next batch's q row into registers (same chunk only)
        {
            const int qn = qloc + 64;
            have_pf = false;
            if (qn < nqL && (qn & 255) != 0) {
                int nbn = min(64, nqL - qn);
                if (jq < nbn) {
                    pe = q_ent[(qn & 255) + jq];
                    const float4* src =
                        (const float4*)(qb + (size_t)(pe & 1023u) * 64 + cq * 16);
                    f0 = src[0]; f1 = src[1]; f2 = src[2]; f3 = src[3];
                    have_pf = true;
                }
            }
        }
        bar_lgkm();                    // (C) staged; prev Ou_bf reads complete

        // MFMA: O[dv][j] = sum_dk M[dv][dk] * Q[j][dk]
        float16v C;
        #pragma unroll
        for (int i = 0; i < 16; ++i) C[i] = 0.f;
        const int am = dvh * 32 + (lane & 31);
        const int bn = jh  * 32 + (lane & 31);
        #pragma unroll
        for (int ks = 0; ks < 4; ++ks) {
            int ch = ks * 2 + hi;
            bf16x8 af = *(const bf16x8*)&M_bf[am * 64 + ((ch ^ (am & 7)) << 3)];
            bf16x8 bf = *(const bf16x8*)&Q_bf[bn * 64 + ((ch ^ (bn & 7)) << 3)];
            C = __builtin_amdgcn_mfma_f32_32x32x16_bf16(af, bf, C, 0, 0, 0);
        }
        // epilogue: scale by w/den, write O^T[j=bn][dv] as bf16
        {
            double den = den_s[bn];
            float  w   = w_s[cur][bn];
            float rinv = (float)((double)w / (den + (double)EPS));
            #pragma unroll
            for (int rq = 0; rq < 4; ++rq) {
                bf16x4 pk;
                pk[0] = (short)f2bf(C[rq * 4 + 0] * rinv);
                pk[1] = (short)f2bf(C[rq * 4 + 1] * rinv);
                pk[2] = (short)f2bf(C[rq * 4 + 2] * rinv);
                pk[3] = (short)f2bf(C[rq * 4 + 3] * rinv);
                *(bf16x4*)&Ou_bf[bn * 68 + dvh * 32 + rq * 8 + hi * 4] = pk;
            }
        }
        bar_lgkm();                    // (D) O ready; Q_bf reads complete
        prev_nb = nb;
    }
    // final flush
    {
        const int cur = (((nqL + 63) >> 6) - 1) & 1;   // parity of last batch
        #pragma unroll
        for (int jj = 0; jj < 16; ++jj) {
            int j = grp * 16 + jj;
            if (j < prev_nb) {
                unsigned short vb16 = Ou_bf[j * 68 + lane];
                int sr = sq_s[cur][j];
                int s  = sr & 1023;
                if constexpr (SC) {
                    int r = (sr >> 10) & 15;
                    if (r < 8)
                        obuf_b[((size_t)s * 8 + r) * 64 + lane] = vb16;
                    else
                        unsafeAtomicAdd(&ob[(size_t)s * 64 + lane],
                            __uint_as_float((unsigned)vb16 << 16));
                } else {
                    unsafeAtomicAdd(&ob[(size_t)s * 64 + lane],
                        __uint_as_float((unsigned)vb16 << 16));
                }
            }
        }
    }
}

// 1024 blocks x 4 waves x 8 queries: sum the 8 rank slots per no-tie query
// (coalesced 128B reads) -> out. Tie rows (qflag) already accumulated via
// atomics onto k_pre's zeroed out.
__global__ __launch_bounds__(256) void k_reduce(const unsigned short* __restrict__ Obuf,
                                                const unsigned char* __restrict__ qflag,
                                                float* __restrict__ out) {
    const int wv   = threadIdx.x >> 6;
    const int lane = threadIdx.x & 63;
    const int q0   = (blockIdx.x * 4 + wv) * 8;
    #pragma unroll
    for (int i = 0; i < 8; ++i) {
        int q = q0 + i;
        if (qflag[q]) continue;                // atomic-accumulated row
        const unsigned short* obr = Obuf + (size_t)q * 512;
        float acc = 0.f;
        #pragma unroll
        for (int r = 0; r < 8; ++r)
            acc += __uint_as_float((unsigned)obr[r * 64 + lane] << 16);
        out[(size_t)q * 64 + lane] = acc;
    }
}

extern "C" void kernel_launch(void* const* d_in, const int* in_sizes, int n_in,
                              void* d_out, int out_size, void* d_ws, size_t ws_size,
                              hipStream_t stream) {
    const float* keys    = (const float*)d_in[0];
    const float* values  = (const float*)d_in[1];
    const float* queries = (const float*)d_in[2];
    char* ws = (char*)d_ws;
    int*            kcnt2  = (int*)(ws);
    int*            qcnt2  = (int*)(ws + 262144);
    unsigned short* klist2 = (unsigned short*)(ws + 524288);
    unsigned*       qpair  = (unsigned*)(ws + 4718592);
    unsigned char*  qflag  = (unsigned char*)(ws + 30416896);
    unsigned short* Obuf   = (unsigned short*)(ws + 30449664);
    const bool big2 = (ws_size >= 64004096u);

    k_pre<<<1024, 512, 0, stream>>>(keys, queries, kcnt2, klist2, qcnt2, qpair,
                                    big2 ? qflag : nullptr, (float*)d_out);
    if (big2) {
        k_mainB<true><<<4096, 256, 0, stream>>>(keys, values, queries, kcnt2,
                                                klist2, qcnt2, qpair, Obuf,
                                                (float*)d_out);
        k_reduce<<<1024, 256, 0, stream>>>(Obuf, qflag, (float*)d_out);
    } else {
        k_mainB<false><<<4096, 256, 0, stream>>>(keys, values, queries, kcnt2,
                                                 klist2, qcnt2, qpair, Obuf,
                                                 (float*)d_out);
    }
}

// Round 12
// 129.628 us; speedup vs baseline: 1.1548x; 1.1548x over previous
//
#include <hip/hip_runtime.h>
#include <math.h>

#define S_LEN 1024
#define EPS 1e-6f

typedef __attribute__((ext_vector_type(8)))  short bf16x8;
typedef __attribute__((ext_vector_type(4)))  short bf16x4;
typedef __attribute__((ext_vector_type(16))) float float16v;

// Workspace layout (bytes):
//   kcnt2  : int  [32*64*32]      @ 0          (262144)  [bh][dim][seg]
//   qcnt2  : int  [32*64*32]      @ 262144     (262144)  [bh][dim][seg]
//   klist2 : ushort [2048*1024]   @ 524288     (4194304) [(bh,dim)][seg*32+pos]
//   qpair  : uint [2048*1024]     @ 4718592    (8388608) packed (w18|rank4|s10)
//   --- scatter extension (ws_size >= 64004096) ---
//   qflag  : uchar [32768]        @ 30416896   (32768)   1 = tie row (atomic path)
//   Obuf   : ushort [32768*8*64]  @ 30449664   (33554432) bf16 rank-slot rows
// R12 = R10 verbatim (best verified, 130.3us). R11's NSPLIT=2 regressed
// (fixed per-block prefix doubled in aggregate; occupancy capped by LDS
// residency, not queue depth) and is reverted. Session floor: harness fill
// ~45us (immovable) + k_pre ~35 + k_mainB ~40 + k_reduce ~8.

// lgkm-only barrier: __syncthreads() would force vmcnt(0), draining in-flight
// global stores/atomics + prefetch loads. Intra-block hazards here are
// LDS-only; global loads are register-consumed (compiler inserts counted
// vmcnt); stores/atomics are never read back in-kernel.
__device__ __forceinline__ void bar_lgkm() {
    asm volatile("s_waitcnt lgkmcnt(0)" ::: "memory");
    __builtin_amdgcn_s_barrier();
    __builtin_amdgcn_sched_barrier(0);
    asm volatile("" ::: "memory");
}

// VGPR anchor (rule #17): forces materialization at this program point
// (defeats load-sinking; R3 k_pre VGPR=20 showed loads sunk into loops).
#define PIN(x) asm volatile("" : "+v"(x))

__device__ __forceinline__ unsigned short f2bf(float f) {
    unsigned int u = __float_as_uint(f);
    unsigned int r = (u + 0x7fffu + ((u >> 16) & 1u)) >> 16;
    return (unsigned short)r;
}

__device__ __forceinline__ bf16x8 pack8(float4 a, float4 b) {
    bf16x8 r;
    r[0] = (short)f2bf(a.x); r[1] = (short)f2bf(a.y);
    r[2] = (short)f2bf(a.z); r[3] = (short)f2bf(a.w);
    r[4] = (short)f2bf(b.x); r[5] = (short)f2bf(b.y);
    r[6] = (short)f2bf(b.z); r[7] = (short)f2bf(b.w);
    return r;
}

// 1024 blocks = (bh, seg), 512 threads = 8 waves x 4 positions.
__global__ __launch_bounds__(512) void k_pre(const float* __restrict__ keys,
                                             const float* __restrict__ queries,
                                             int* __restrict__ kcnt2,
                                             unsigned short* __restrict__ klist2,
                                             int* __restrict__ qcnt2,
                                             unsigned* __restrict__ qpair,
                                             unsigned char* __restrict__ qflag,
                                             float* __restrict__ out) {
    const int bh   = blockIdx.x >> 5;
    const int blk  = blockIdx.x & 31;          // segment id
    const int wv   = threadIdx.x >> 6;         // 0..7
    const int lane = threadIdx.x & 63;

    __shared__ int khist[64], qhist[64];
    __shared__ alignas(16) unsigned rq_s[8][4][64];   // 8 KB: per-wave row stage
    if (threadIdx.x < 64) { khist[threadIdx.x] = 0; qhist[threadIdx.x] = 0; }
    __syncthreads();

    const int s0 = blk * 32 + wv * 4;
    float kv[4], qv[4];
    #pragma unroll
    for (int i = 0; i < 4; ++i) {              // all loads issued up-front
        kv[i] = keys   [((size_t)bh * 1024 + s0 + i) * 64 + lane];
        qv[i] = queries[((size_t)bh * 1024 + s0 + i) * 64 + lane];
    }

    // zero d_out slice (independent store, issues inside the load shadow)
    {
        float4 zz = {0.f, 0.f, 0.f, 0.f};
        float4* po = (float4*)(out + (size_t)blockIdx.x * 2048);
        po[threadIdx.x] = zz;
    }

    // anchor: one vmcnt wait for all 8 loads; compute below is register/LDS
    #pragma unroll
    for (int i = 0; i < 4; ++i) { PIN(kv[i]); PIN(qv[i]); }

    // stage |q| bits to LDS (wave-private rows)
    unsigned ud[4];
    #pragma unroll
    for (int i = 0; i < 4; ++i) {
        ud[i] = __float_as_uint(qv[i]) & 0x7fffffffu;
        rq_s[wv][i][lane] = ud[i];
    }

    // ---- keys: 4 interleaved wave-argmaxes ----
    float bv[4]; int bi[4];
    #pragma unroll
    for (int i = 0; i < 4; ++i) { bv[i] = fabsf(kv[i]); bi[i] = lane; }
    #pragma unroll
    for (int off = 1; off < 64; off <<= 1) {
        #pragma unroll
        for (int i = 0; i < 4; ++i) {
            float ov = __shfl_xor(bv[i], off, 64);
            int   oi = __shfl_xor(bi[i], off, 64);
            if (ov > bv[i] || (ov == bv[i] && oi < bi[i])) { bv[i] = ov; bi[i] = oi; }
        }
    }
    #pragma unroll
    for (int i = 0; i < 4; ++i) {
        if (lane == 0) {
            int pos = atomicAdd(&khist[bi[i]], 1);
            klist2[((size_t)bh * 64 + bi[i]) * 1024 + blk * 32 + pos] =
                (unsigned short)(s0 + i);
        }
    }

    // ---- queries: rank via LDS uint4 broadcast (same-addr, conflict-free) ----
    int gt[4] = {0, 0, 0, 0};
    #pragma unroll
    for (int k4 = 0; k4 < 16; ++k4) {
        #pragma unroll
        for (int i = 0; i < 4; ++i) {
            const uint4 vv = *(const uint4*)&rq_s[wv][i][k4 * 4];
            gt[i] += (vv.x > ud[i]) ? 1 : 0;
            gt[i] += (vv.y > ud[i]) ? 1 : 0;
            gt[i] += (vv.z > ud[i]) ? 1 : 0;
            gt[i] += (vv.w > ud[i]) ? 1 : 0;
        }
    }
    int S[4];                                  // permutation check for ties
    #pragma unroll
    for (int i = 0; i < 4; ++i) S[i] = gt[i];
    #pragma unroll
    for (int off = 1; off < 64; off <<= 1) {
        #pragma unroll
        for (int i = 0; i < 4; ++i) S[i] += __shfl_xor(S[i], off, 64);
    }
    float e[4];
    #pragma unroll
    for (int i = 0; i < 4; ++i) e[i] = expf(__uint_as_float(ud[i]));
    int copies[4], contrib[4], rank[4];
    #pragma unroll
    for (int i = 0; i < 4; ++i) {
        if (S[i] == 2016) {                    // no ties (wave-uniform branch)
            contrib[i] = (gt[i] < 8);
            copies[i]  = contrib[i] ? 2 : 0;
            rank[i]    = gt[i];                // unique slot 0..7
        } else {                               // exact tie handling (rare)
            int eq = 0, eql = 0;
            #pragma unroll
            for (int k = 0; k < 64; ++k) {
                unsigned ui = (unsigned)__builtin_amdgcn_readlane((int)ud[i], k);
                eq  += (ui == ud[i]) ? 1 : 0;
                eql += (ui == ud[i] && k < lane) ? 1 : 0;
            }
            int pos_low  = 2 * gt[i] + eql;
            int pos_high = pos_low + eq;       // eq includes self
            copies[i]  = (pos_low < 16 ? 1 : 0) + (pos_high < 16 ? 1 : 0);
            contrib[i] = (pos_low < 16);
            rank[i]    = 15;                   // sentinel -> atomic path
        }
    }
    float ce[4];
    #pragma unroll
    for (int i = 0; i < 4; ++i) ce[i] = (float)copies[i] * e[i];
    #pragma unroll
    for (int off = 1; off < 64; off <<= 1) {
        #pragma unroll
        for (int i = 0; i < 4; ++i) ce[i] += __shfl_xor(ce[i], off, 64);
    }
    #pragma unroll
    for (int i = 0; i < 4; ++i) {
        if (contrib[i]) {
            int pos = atomicAdd(&qhist[lane], 1);
            unsigned wb = __float_as_uint(e[i] / ce[i]) & 0xFFFFC000u;  // 18-bit w
            qpair[((size_t)bh * 64 + lane) * 1024 + blk * 32 + pos] =
                wb | ((unsigned)rank[i] << 10) | (unsigned)(s0 + i);
        }
        if (qflag && lane == 0)
            qflag[bh * 1024 + s0 + i] = (S[i] == 2016) ? 0 : 1;
    }
    __syncthreads();
    if (threadIdx.x < 64) {                    // transposed [bh][dim][seg]
        kcnt2[(bh * 64 + threadIdx.x) * 32 + blk] = khist[threadIdx.x];
        qcnt2[(bh * 64 + threadIdx.x) * 32 + blk] = qhist[threadIdx.x];
    }
}

// 2048 blocks = (bh, bank), fused build + query. Build stages a whole 32-key
// chunk at once (1 parallel RT, 1 barrier) into f32 scratch aliased onto
// Q_bf (k) and Ou_bf (v), which are dead until the query loop. SC: flush ->
// rank-addressed Obuf slots (plain stores); rank-15 ties -> atomics;
// k_reduce sums.
template <bool SC>
__global__ __launch_bounds__(256) void k_mainB(const float* __restrict__ keys,
                                               const float* __restrict__ values,
                                               const float* __restrict__ queries,
                                               const int* __restrict__ kcnt2,
                                               const unsigned short* __restrict__ klist2,
                                               const int* __restrict__ qcnt2,
                                               const unsigned* __restrict__ qpair,
                                               unsigned short* __restrict__ Obuf,
                                               float* __restrict__ out) {
    const int g     = blockIdx.x;      // 0..2047 = (bh, bank)
    const int bh    = g >> 6;
    const int bank  = g & 63;
    const int t     = threadIdx.x;
    const int lane  = t & 63;
    const int grp   = t >> 6;

    __shared__ alignas(16) unsigned short M_bf[64 * 64];   // 8 KB
    __shared__ alignas(16) unsigned short Q_bf[64 * 64];   // 8 KB (build: k-scratch f32)
    __shared__ alignas(16) unsigned short Ou_bf[64 * 68];  // 8.7 KB (build: v-scratch f32)
    __shared__ unsigned short s_match[256];
    __shared__ unsigned q_ent[256];
    __shared__ int    koffs_s[33], qoffs_s[33];
    __shared__ float  z_s[64];
    __shared__ double den_s[64];
    __shared__ float  w_s[2][64];
    __shared__ int    sq_s[2][64];

    // dual prefix scan: lanes 0-31 keys, 32-63 queries (contiguous counts)
    if (t < 64) {
        int i = t & 31;
        int c = (t < 32) ? kcnt2[(bh * 64 + bank) * 32 + i]
                         : qcnt2[(bh * 64 + bank) * 32 + i];
        #pragma unroll
        for (int off = 1; off < 32; off <<= 1) {
            int o = __shfl(c, t - off, 64);    // guarded by i >= off
            if (i >= off) c += o;
        }
        if (t < 32) { if (i == 0) koffs_s[0] = 0; koffs_s[i + 1] = c; }
        else        { if (i == 0) qoffs_s[0] = 0; qoffs_s[i + 1] = c; }
    }
    bar_lgkm();

    const int nq = qoffs_s[32];
    const int nm = koffs_s[32];
    if (nq == 0) return;
    const size_t listbase = (size_t)(bh * 64 + bank) * 1024;
    if (nm == 0) {
        // SC: empty bank still owns Obuf slots for its entries -> zero-fill
        if constexpr (SC) {
            for (int jg = t; jg < nq; jg += 256) {
                int seg = 0;
                #pragma unroll
                for (int i = 1; i < 32; ++i) if (jg >= qoffs_s[i]) seg = i;
                unsigned e = qpair[listbase + seg * 32 + (jg - qoffs_s[seg])];
                int r = (e >> 10) & 15;
                if (r < 8) {
                    uint4 z4 = {0u, 0u, 0u, 0u};
                    uint4* dst = (uint4*)&Obuf[(((size_t)bh * 1024 +
                                 (e & 1023u)) * 8 + r) * 64];
                    #pragma unroll
                    for (int x = 0; x < 8; ++x) dst[x] = z4;
                }
            }
        }
        return;
    }

    // ---- phase 2: both chunk-0 gathers issued together (one bar) ----
    {
        if (t < min(256, nm)) {                // klist chunk 0
            int seg = 0;
            #pragma unroll
            for (int i = 1; i < 32; ++i) if (t >= koffs_s[i]) seg = i;
            s_match[t] = klist2[listbase + seg * 32 + (t - koffs_s[seg])];
        }
        if (t < min(256, nq)) {                // q_ent chunk 0 (hides under build)
            int seg = 0;
            #pragma unroll
            for (int i = 1; i < 32; ++i) if (t >= qoffs_s[i]) seg = i;
            q_ent[t] = qpair[listbase + seg * 32 + (t - qoffs_s[seg])];
        }
    }
    bar_lgkm();

    // ---- build M[dv][dk] = sum_s v[s][dv]*k[s][dk], z[dk] = sum_s k[s][dk]
    // whole 32-key chunk staged at once -> 1 parallel RT + 1 barrier.
    //   thread t: row r = t>>3, col-octet c8 = t&7 (2 float4 each of k and v)
    {
        float* kstf = (float*)Q_bf;            // 32x64 f32 = 8 KB (Q_bf dead)
        float* vstf = (float*)Ou_bf;           // 32x64 f32 = 8 KB (Ou_bf dead)
        float acc[16];
        #pragma unroll
        for (int m = 0; m < 16; ++m) acc[m] = 0.f;
        float zacc = 0.f;
        const float* kb = keys   + (size_t)bh * S_LEN * 64;
        const float* vb = values + (size_t)bh * S_LEN * 64;
        int win = 0;                           // s_match window base
        for (int cb = 0; cb < nm; cb += 32) {
            const int cn = min(32, nm - cb);
            if ((cb & ~255) != win) {          // refill window (nm>256: ~never)
                bar_lgkm();
                win = cb & ~255;
                int wn = min(256, nm - win);
                if (t < wn) {
                    int idx = win + t, seg = 0;
                    #pragma unroll
                    for (int i = 1; i < 32; ++i) if (idx >= koffs_s[i]) seg = i;
                    s_match[t] = klist2[listbase + seg * 32 + (idx - koffs_s[seg])];
                }
                bar_lgkm();
            }
            if (cb > 0) bar_lgkm();            // prev chunk's scratch reads done
            {
                int r = t >> 3, c8 = t & 7;
                if (r < cn) {
                    int s = s_match[(cb - win) + r];
                    const float4* ks = (const float4*)(kb + (size_t)s * 64 + c8 * 8);
                    float4 k0 = ks[0], k1 = ks[1];
                    const float4* vs = (const float4*)(vb + (size_t)s * 64 + c8 * 8);
                    float4 w0 = vs[0], w1 = vs[1];
                    float4* kd = (float4*)&kstf[r * 64 + c8 * 8];
                    kd[0] = k0; kd[1] = k1;
                    float4* vd = (float4*)&vstf[r * 64 + c8 * 8];
                    vd[0] = w0; vd[1] = w1;
                }
            }
            bar_lgkm();                        // staging visible (1 barrier/chunk)
            for (int r = 0; r < cn; ++r) {
                float kv = kstf[r * 64 + lane];        // dk = lane (coalesced)
                #pragma unroll
                for (int m = 0; m < 16; ++m)           // dv = grp*16+m (broadcast)
                    acc[m] += vstf[r * 64 + grp * 16 + m] * kv;
            }
            if (t < 64)
                for (int r = 0; r < cn; ++r) zacc += kstf[r * 64 + t];
        }
        // write M as bf16, row-major [dv][dk], 16B-chunk XOR swizzle
        #pragma unroll
        for (int m = 0; m < 16; ++m) {
            int dv = grp * 16 + m;
            M_bf[dv * 64 + (((lane >> 3) ^ (dv & 7)) << 3) + (lane & 7)] = f2bf(acc[m]);
        }
        if (t < 64) z_s[t] = zacc;
    }
    bar_lgkm();                        // M_bf/z_s visible; scratch reads done

    // ---- query loop over [0, nq): pipelined + prefetched ----
    const float* qb = queries + (size_t)bh * S_LEN * 64;
    float*       ob = out     + (size_t)bh * S_LEN * 64;
    unsigned short* obuf_b = SC ? Obuf + (size_t)bh * 1024 * 512 : nullptr;
    const int dvh = grp >> 1, jh = grp & 1;            // wave's 32x32 tile
    const int hi  = lane >> 5;
    const int jq  = t >> 2, cq = t & 3;                // stage mapping

    int prev_nb = 0;
    bool have_pf = false;                              // next-batch q row in regs
    float4 f0, f1, f2, f3;
    unsigned pe = 0;
    for (int qloc = 0, batch = 0; qloc < nq; qloc += 64, ++batch) {
        const int nb  = min(64, nq - qloc);
        const int cur = batch & 1;

        if (qloc != 0 && (qloc & 255) == 0) {  // refill q_ent past chunk 0
            if (qloc + t < nq) {
                int jg = qloc + t;
                int seg = 0;
                #pragma unroll
                for (int i = 1; i < 32; ++i) if (jg >= qoffs_s[i]) seg = i;
                q_ent[t] = qpair[listbase + seg * 32 + (jg - qoffs_s[seg])];
            }
            bar_lgkm();
        }

        // A1: entry + cold q loads issued FIRST (don't queue behind stores)
        unsigned e = 0;
        const bool act = (jq < nb);
        if (act) {
            e = have_pf ? pe : q_ent[(qloc & 255) + jq];
            if (!have_pf) {
                const float4* src =
                    (const float4*)(qb + (size_t)(e & 1023u) * 64 + cq * 16);
                f0 = src[0]; f1 = src[1]; f2 = src[2]; f3 = src[3];
            }
        }

        // A2: flush previous batch (SC: plain bf16 stores to rank slots;
        // rank-15 tie entries keep atomic add; fire-and-forget either way)
        if (batch > 0) {
            #pragma unroll
            for (int jj = 0; jj < 16; ++jj) {
                int j = grp * 16 + jj;
                if (j < prev_nb) {
                    unsigned short vb16 = Ou_bf[j * 68 + lane];
                    int sr = sq_s[1 - cur][j];
                    int s  = sr & 1023;
                    if constexpr (SC) {
                        int r = (sr >> 10) & 15;
                        if (r < 8)
                            obuf_b[((size_t)s * 8 + r) * 64 + lane] = vb16;
                        else
                            unsafeAtomicAdd(&ob[(size_t)s * 64 + lane],
                                __uint_as_float((unsigned)vb16 << 16));
                    } else {
                        unsafeAtomicAdd(&ob[(size_t)s * 64 + lane],
                            __uint_as_float((unsigned)vb16 << 16));
                    }
                }
            }
        }

        // A3: pack + denominator + LDS stage
        {
            bf16x8 p0 = {}, p1 = {};
            double d = 0.0;
            if (act) {
                if ((t & 3) == 0) {
                    sq_s[cur][jq] = (int)(e & 0x3FFFu);        // s | rank<<10
                    w_s[cur][jq]  = __uint_as_float(e & 0xFFFFC000u);
                }
                p0 = pack8(f0, f1);
                p1 = pack8(f2, f3);
                const float4* zz4 = (const float4*)&z_s[cq * 16];
                float4 z0 = zz4[0], z1 = zz4[1], z2 = zz4[2], z3 = zz4[3];
                double da, db;
                da  = (double)z0.x * f0.x + (double)z0.y * f0.y + (double)z0.z * f0.z + (double)z0.w * f0.w;
                db  = (double)z1.x * f1.x + (double)z1.y * f1.y + (double)z1.z * f1.z + (double)z1.w * f1.w;
                da += (double)z2.x * f2.x + (double)z2.y * f2.y + (double)z2.z * f2.z + (double)z2.w * f2.w;
                db += (double)z3.x * f3.x + (double)z3.y * f3.y + (double)z3.z * f3.z + (double)z3.w * f3.w;
                d = da + db;
            }
            int c0 = cq * 2;
            *(bf16x8*)&Q_bf[jq * 64 + ((c0 ^ (jq & 7)) << 3)]       = p0;
            *(bf16x8*)&Q_bf[jq * 64 + (((c0 + 1) ^ (jq & 7)) << 3)] = p1;
            d += __shfl_xor(d, 1, 64);
            d += __shfl_xor(d, 2, 64);
            if ((t & 3) == 0) den_s[jq] = d;
        }

        // A4: prefetch next batch's q row into registers (same chunk only)
        {
            const int qn = qloc + 64;
            have_pf = false;
            if (qn < nq && (qn & 255) != 0) {
                int nbn = min(64, nq - qn);
                if (jq < nbn) {
                    pe = q_ent[(qn & 255) + jq];
                    const float4* src =
                        (const float4*)(qb + (size_t)(pe & 1023u) * 64 + cq * 16);
                    f0 = src[0]; f1 = src[1]; f2 = src[2]; f3 = src[3];
                    have_pf = true;
                }
            }
        }
        bar_lgkm();                    // (C) staged; prev Ou_bf reads complete

        // MFMA: O[dv][j] = sum_dk M[dv][dk] * Q[j][dk]
        float16v C;
        #pragma unroll
        for (int i = 0; i < 16; ++i) C[i] = 0.f;
        const int am = dvh * 32 + (lane & 31);
        const int bn = jh  * 32 + (lane & 31);
        #pragma unroll
        for (int ks = 0; ks < 4; ++ks) {
            int ch = ks * 2 + hi;
            bf16x8 af = *(const bf16x8*)&M_bf[am * 64 + ((ch ^ (am & 7)) << 3)];
            bf16x8 bf = *(const bf16x8*)&Q_bf[bn * 64 + ((ch ^ (bn & 7)) << 3)];
            C = __builtin_amdgcn_mfma_f32_32x32x16_bf16(af, bf, C, 0, 0, 0);
        }
        // epilogue: scale by w/den, write O^T[j=bn][dv] as bf16
        {
            double den = den_s[bn];
            float  w   = w_s[cur][bn];
            float rinv = (float)((double)w / (den + (double)EPS));
            #pragma unroll
            for (int rq = 0; rq < 4; ++rq) {
                bf16x4 pk;
                pk[0] = (short)f2bf(C[rq * 4 + 0] * rinv);
                pk[1] = (short)f2bf(C[rq * 4 + 1] * rinv);
                pk[2] = (short)f2bf(C[rq * 4 + 2] * rinv);
                pk[3] = (short)f2bf(C[rq * 4 + 3] * rinv);
                *(bf16x4*)&Ou_bf[bn * 68 + dvh * 32 + rq * 8 + hi * 4] = pk;
            }
        }
        bar_lgkm();                    // (D) O ready; Q_bf reads complete
        prev_nb = nb;
    }
    // final flush
    {
        const int cur = (((nq + 63) >> 6) - 1) & 1;    // parity of last batch
        #pragma unroll
        for (int jj = 0; jj < 16; ++jj) {
            int j = grp * 16 + jj;
            if (j < prev_nb) {
                unsigned short vb16 = Ou_bf[j * 68 + lane];
                int sr = sq_s[cur][j];
                int s  = sr & 1023;
                if constexpr (SC) {
                    int r = (sr >> 10) & 15;
                    if (r < 8)
                        obuf_b[((size_t)s * 8 + r) * 64 + lane] = vb16;
                    else
                        unsafeAtomicAdd(&ob[(size_t)s * 64 + lane],
                            __uint_as_float((unsigned)vb16 << 16));
                } else {
                    unsafeAtomicAdd(&ob[(size_t)s * 64 + lane],
                        __uint_as_float((unsigned)vb16 << 16));
                }
            }
        }
    }
}

// 1024 blocks x 4 waves x 8 queries: sum the 8 rank slots per no-tie query
// (coalesced 128B reads) -> out. Tie rows (qflag) already accumulated via
// atomics onto k_pre's zeroed out.
__global__ __launch_bounds__(256) void k_reduce(const unsigned short* __restrict__ Obuf,
                                                const unsigned char* __restrict__ qflag,
                                                float* __restrict__ out) {
    const int wv   = threadIdx.x >> 6;
    const int lane = threadIdx.x & 63;
    const int q0   = (blockIdx.x * 4 + wv) * 8;
    #pragma unroll
    for (int i = 0; i < 8; ++i) {
        int q = q0 + i;
        if (qflag[q]) continue;                // atomic-accumulated row
        const unsigned short* obr = Obuf + (size_t)q * 512;
        float acc = 0.f;
        #pragma unroll
        for (int r = 0; r < 8; ++r)
            acc += __uint_as_float((unsigned)obr[r * 64 + lane] << 16);
        out[(size_t)q * 64 + lane] = acc;
    }
}

extern "C" void kernel_launch(void* const* d_in, const int* in_sizes, int n_in,
                              void* d_out, int out_size, void* d_ws, size_t ws_size,
                              hipStream_t stream) {
    const float* keys    = (const float*)d_in[0];
    const float* values  = (const float*)d_in[1];
    const float* queries = (const float*)d_in[2];
    char* ws = (char*)d_ws;
    int*            kcnt2  = (int*)(ws);
    int*            qcnt2  = (int*)(ws + 262144);
    unsigned short* klist2 = (unsigned short*)(ws + 524288);
    unsigned*       qpair  = (unsigned*)(ws + 4718592);
    unsigned char*  qflag  = (unsigned char*)(ws + 30416896);
    unsigned short* Obuf   = (unsigned short*)(ws + 30449664);
    const bool big2 = (ws_size >= 64004096u);

    k_pre<<<1024, 512, 0, stream>>>(keys, queries, kcnt2, klist2, qcnt2, qpair,
                                    big2 ? qflag : nullptr, (float*)d_out);
    if (big2) {
        k_mainB<true><<<2048, 256, 0, stream>>>(keys, values, queries, kcnt2,
                                                klist2, qcnt2, qpair, Obuf,
                                                (float*)d_out);
        k_reduce<<<1024, 256, 0, stream>>>(Obuf, qflag, (float*)d_out);
    } else {
        k_mainB<false><<<2048, 256, 0, stream>>>(keys, values, queries, kcnt2,
                                                 klist2, qcnt2, qpair, Obuf,
                                                 (float*)d_out);
    }
}